// Round 10
// baseline (102.118 us; speedup 1.0000x reference)
//
#include <hip/hip_runtime.h>

#define B 8192
#define F 128
#define H 64

typedef __attribute__((ext_vector_type(8))) short bf16x8;
typedef __attribute__((ext_vector_type(4))) float f32x4;

static __device__ __forceinline__ unsigned short f32_to_bf16_rne(float v) {
    unsigned int u = __float_as_uint(v);
    unsigned int r = (u + 0x7FFFu + ((u >> 16) & 1u)) >> 16;
    return (unsigned short)r;
}
static __device__ __forceinline__ float bf16_to_f32(unsigned short h) {
    return __uint_as_float(((unsigned int)h) << 16);
}

// global->LDS DMA; LDS dest is wave-uniform base + lane*size (linear);
// global src is PER-LANE (strided gathers allowed).
#define GLOAD_LDS16(gp, lp)                                                  \
    __builtin_amdgcn_global_load_lds(                                        \
        (const __attribute__((address_space(1))) unsigned int*)(gp),         \
        (__attribute__((address_space(3))) unsigned int*)(lp), 16, 0, 0)
#define GLOAD_LDS4(gp, lp)                                                   \
    __builtin_amdgcn_global_load_lds(                                        \
        (const __attribute__((address_space(1))) unsigned int*)(gp),         \
        (__attribute__((address_space(3))) unsigned int*)(lp), 4, 0, 0)

// Split-bf16 MFMA NAM.  Layer2 = 3x mfma_f32_16x16x32_bf16 (hh + hl + lh).
// R14: R11 (occupancy), R12 (unroll, +1), R13 (x->LDS) all ~null => the mt
// loop is near its issue floor (~9us chip-wide) and waves already cover
// in-loop latency.  Last untested structural term: block-startup
// serialization -- 2048 blocks over ~768-1024 slots = 2-2.7 dispatch
// rounds, each block paying DMA->barrier->fragload (~1.5-2us) that cannot
// be hidden within the block.  Single change: grid (16,F) -> (8,F):
// 1024 blocks = 256 CU x 4 blocks/CU, ENTIRE grid co-resident, startup
// paid once in parallel, zero re-dispatch rounds.  Fits proven limits:
// LDS 38.4KB x 4 = 153.6 <= 160KB; VGPR 80 allows 16 waves/CU (m69 band;
// R11 ran 4 blocks/CU at 80 VGPR).  1024 rows/block, 16 mt, reduce every
// 4 mt.  Numerics identical -> absmax 0.0625.
// Hard rules kept: __launch_bounds__(256,3) ONLY ((256,4) -> 64-VGPR spill
// catastrophe, twice measured); LDS table via global_load_lds (linear
// dest); fire-and-forget LDS scatter epilogue + per-64-row reduce (no
// shfl chains); ws guard + R4-mono fallback; no memset in fast path.

// ---- prep: F blocks: W2 (H,H) f32 -> hi/lo bf16 B-fragment table ----
__global__ __launch_bounds__(256) void nam_prep(
    const float* __restrict__ W2, short* __restrict__ bhi_g,
    short* __restrict__ blo_g)
{
    const int tid = threadIdx.x;
    const int f = blockIdx.x;
    const float* W2f = W2 + (size_t)f * H * H;
    short* bhi = bhi_g + (size_t)f * 4096;
    short* blo = blo_g + (size_t)f * 4096;
#pragma unroll
    for (int t = tid; t < 512; t += 256) {
        const int n = t & 63;          // output hidden index (MFMA n)
        const int g = t >> 6;          // h-group: h = g*8 + jj (MFMA k)
        const int nt = n >> 4, c = n & 15;
        const int ks = g >> 2, q = g & 3;
        const int slot = (nt * 2 + ks) * 64 + c + 16 * q;
        bf16x8 hv, lv;
#pragma unroll
        for (int jj = 0; jj < 8; ++jj) {
            const float wv = W2f[(g * 8 + jj) * H + n];
            const unsigned short hi = f32_to_bf16_rne(wv);
            const unsigned short lo = f32_to_bf16_rne(wv - bf16_to_f32(hi));
            hv[jj] = (short)hi;
            lv[jj] = (short)lo;
        }
        *(bf16x8*)&bhi[slot * 8] = hv;
        *(bf16x8*)&blo[slot * 8] = lv;
    }
}

__global__ __launch_bounds__(256, 3) void nam_main(
    const float* __restrict__ inputs, const float* __restrict__ W1,
    const float* __restrict__ b1, const short* __restrict__ bhi_g,
    const short* __restrict__ blo_g, const float* __restrict__ b2,
    const float* __restrict__ W3, const float* __restrict__ b3,
    float* __restrict__ fnn_ws)
{
    const int tid = threadIdx.x;
    const int f = blockIdx.y;
    const int b0 = blockIdx.x * 1024;  // 1024 rows per block (single round)

    const int lane = tid & 63;
    const int w    = tid >> 6;
    const int q    = lane >> 4;   // quad
    const int col  = lane & 15;

    // per-wave partial-sum tile, 64 rows: row = (mt&3)*16+4q+reg, 16 cols,
    // pad to 18 f32 -> <=2-way bank aliasing (free).  Reduced every 4 mt.
    __shared__ float s_tile[4][64][18];         // 18432 B
    __shared__ __align__(16) short bhs[4096];   // 8 KB
    __shared__ __align__(16) short bls[4096];   // 8 KB
    __shared__ float x_lds[4][256];             // 4 KB: per-wave x values

    // ---- DMA: table slice (16KB) + this wave's 256 x values, one drain ----
    {
        const short* bhi_f = bhi_g + (size_t)f * 4096;
        const short* blo_f = blo_g + (size_t)f * 4096;
#pragma unroll
        for (int c = w; c < 8; c += 4) {      // 2 chunks/table/wave
            GLOAD_LDS16(bhi_f + c * 512 + lane * 8, &bhs[c * 512]);
            GLOAD_LDS16(blo_f + c * 512 + lane * 8, &bls[c * 512]);
        }
        // x stage: rows [b0 + w*256, +256), strided 512B per-lane src,
        // linear lane*4 LDS dest.  Same addresses/bits as per-mt gathers.
#pragma unroll
        for (int c = 0; c < 4; ++c)
            GLOAD_LDS4(inputs + (size_t)(b0 + w * 256 + c * 64 + lane) * F + f,
                       &x_lds[w][c * 64]);
    }

    // per-lane weight vectors (L2-hot broadcasts; overlap with DMA)
    const float* W1f = W1 + f * H;
    const float* b1f = b1 + f * H;
    float w1v[16], b1v[16];
#pragma unroll
    for (int ks = 0; ks < 2; ++ks)
#pragma unroll
        for (int j = 0; j < 8; ++j) {
            w1v[ks * 8 + j] = W1f[ks * 32 + q * 8 + j];
            b1v[ks * 8 + j] = b1f[ks * 32 + q * 8 + j];
        }
    const float* b2f = b2 + f * H;
    const float* W3f = W3 + f * H;
    float b2v[4], w3v[4];
#pragma unroll
    for (int nt = 0; nt < 4; ++nt) {
        b2v[nt] = b2f[nt * 16 + col];
        w3v[nt] = W3f[nt * 16 + col];
    }
    const float b3f = b3[f];

    __syncthreads();   // drains table DMA + x DMA together

    // ---- resident B fragments (LDS -> regs, once per block) ----
    bf16x8 bhi[4][2], blo[4][2];
#pragma unroll
    for (int nt = 0; nt < 4; ++nt)
#pragma unroll
        for (int ks = 0; ks < 2; ++ks) {
            const int slot = (nt * 2 + ks) * 64 + lane;
            bhi[nt][ks] = *(bf16x8*)&bhs[slot * 8];
            blo[nt][ks] = *(bf16x8*)&bls[slot * 8];
        }

    // ---- 16 m-tiles of 16 rows per wave; ZERO global loads in loop ----
#pragma unroll 2
    for (int mt = 0; mt < 16; ++mt) {
        // x via LDS: 16 addrs x 4-lane same-address multicast, conflict-free
        const float x = x_lds[w][(mt << 4) | col];

        f32x4 acc[4];
#pragma unroll
        for (int nt = 0; nt < 4; ++nt) {
            acc[nt][0] = b2v[nt]; acc[nt][1] = b2v[nt];
            acc[nt][2] = b2v[nt]; acc[nt][3] = b2v[nt];
        }

#pragma unroll
        for (int ks = 0; ks < 2; ++ks) {
            // A-frag: trunc-Dekker split, v_perm pair-packing.
            union { unsigned int u[4]; bf16x8 v; } Ah, Al;
#pragma unroll
            for (int t = 0; t < 4; ++t) {
                const float r0 = fmaxf(fmaf(x, w1v[ks * 8 + 2 * t],     b1v[ks * 8 + 2 * t]),     0.0f);
                const float r1 = fmaxf(fmaf(x, w1v[ks * 8 + 2 * t + 1], b1v[ks * 8 + 2 * t + 1]), 0.0f);
                const unsigned int u0 = __float_as_uint(r0);
                const unsigned int u1 = __float_as_uint(r1);
                const float l0 = r0 - __uint_as_float(u0 & 0xFFFF0000u);
                const float l1 = r1 - __uint_as_float(u1 & 0xFFFF0000u);
                Ah.u[t] = __builtin_amdgcn_perm(u1, u0, 0x07060302);
                Al.u[t] = __builtin_amdgcn_perm(__float_as_uint(l1),
                                                __float_as_uint(l0), 0x07060302);
            }
#pragma unroll
            for (int nt = 0; nt < 4; ++nt) {
                acc[nt] = __builtin_amdgcn_mfma_f32_16x16x32_bf16(Ah.v, bhi[nt][ks], acc[nt], 0, 0, 0);
                acc[nt] = __builtin_amdgcn_mfma_f32_16x16x32_bf16(Ah.v, blo[nt][ks], acc[nt], 0, 0, 0);
                acc[nt] = __builtin_amdgcn_mfma_f32_16x16x32_bf16(Al.v, bhi[nt][ks], acc[nt], 0, 0, 0);
            }
        }

        // ---- epilogue: fold W3 and scatter partials (fire-and-forget) ----
#pragma unroll
        for (int reg = 0; reg < 4; ++reg) {
            float t = 0.0f;
#pragma unroll
            for (int nt = 0; nt < 4; ++nt)
                t = fmaf(fmaxf(acc[nt][reg], 0.0f), w3v[nt], t);
            s_tile[w][(mt & 3) * 16 + 4 * q + reg][col] = t;
        }

        // ---- per-64-row reduce: 1 row/lane; coalesced 256B store ----
        if ((mt & 3) == 3) {
            float sum = 0.0f;
#pragma unroll
            for (int c = 0; c < 16; ++c)
                sum += s_tile[w][lane][c];
            float* dst = fnn_ws + (size_t)f * B + b0 + w * 256 + (mt >> 2) * 64;
            dst[lane] = sum + b3f;
        }
    }
}

// ---- finish: fnn_ws (F,B) -> fnn (B,F) transpose + out row-sums ----
// 128 blocks, each handles 64 rows x all 128 features: 'out' needs no
// atomics (full sum local to block) and no prior memset.
__global__ __launch_bounds__(256) void nam_finish(
    const float* __restrict__ fnn_ws, float* __restrict__ fnn,
    float* __restrict__ out)
{
    const int tid = threadIdx.x;
    const int r0 = blockIdx.x * 64;
    __shared__ float tile[128][65];    // 33280 B
    __shared__ float psum[4][64];

    float rsum = 0.0f;
#pragma unroll
    for (int j = 0; j < 32; ++j) {     // coalesced 256B/64-lane reads
        const int fl = j * 4 + (tid >> 6);
        const int rl = tid & 63;
        const float v = fnn_ws[(size_t)fl * B + r0 + rl];
        tile[fl][rl] = v;
        rsum += v;
    }
    psum[tid >> 6][tid & 63] = rsum;
    __syncthreads();
    if (tid < 64)                      // plain store; no atomic, no memset
        out[r0 + tid] = psum[0][tid] + psum[1][tid] + psum[2][tid] + psum[3][tid];

#pragma unroll
    for (int j = 0; j < 8; ++j) {      // fnn rows: 512B-contiguous float4 writes
        const int rl = j * 8 + (tid >> 5);
        const int c4 = tid & 31;
        f32x4 v;
        v[0] = tile[c4 * 4 + 0][rl];
        v[1] = tile[c4 * 4 + 1][rl];
        v[2] = tile[c4 * 4 + 2][rl];
        v[3] = tile[c4 * 4 + 3][rl];
        *(f32x4*)&fnn[(size_t)(r0 + rl) * F + c4 * 4] = v;
    }
}

// ---- fallback: proven R4 monolithic kernel (used only if ws too small) ----
__global__ __launch_bounds__(256, 3) void nam_mono(
    const float* __restrict__ inputs, const float* __restrict__ W1,
    const float* __restrict__ b1, const float* __restrict__ W2,
    const float* __restrict__ b2, const float* __restrict__ W3,
    const float* __restrict__ b3, float* __restrict__ out,
    float* __restrict__ fnn_out)
{
    const int tid = threadIdx.x;
    const int f = blockIdx.y;
    const int b0 = blockIdx.x * 256;

    const float* W1f = W1 + f * H;
    const float* b1f = b1 + f * H;
    const float* W2f = W2 + (size_t)f * H * H;
    const float* b2f = b2 + f * H;
    const float* W3f = W3 + f * H;

    __shared__ __align__(16) short bhi_s[512 * 8];
    __shared__ __align__(16) short blo_s[512 * 8];

#pragma unroll
    for (int t = tid; t < 512; t += 256) {
        const int n = t & 63;
        const int g = t >> 6;
        const int nt = n >> 4, c = n & 15;
        const int ks = g >> 2, q = g & 3;
        const int slot = (nt * 2 + ks) * 64 + c + 16 * q;
        bf16x8 hv, lv;
#pragma unroll
        for (int jj = 0; jj < 8; ++jj) {
            const float wv = W2f[(g * 8 + jj) * H + n];
            const unsigned short hi = f32_to_bf16_rne(wv);
            const unsigned short lo = f32_to_bf16_rne(wv - bf16_to_f32(hi));
            hv[jj] = (short)hi;
            lv[jj] = (short)lo;
        }
        *(bf16x8*)&bhi_s[slot * 8] = hv;
        *(bf16x8*)&blo_s[slot * 8] = lv;
    }

    const int lane = tid & 63;
    const int w    = tid >> 6;
    const int q    = lane >> 4;
    const int col  = lane & 15;

    float w1v[16], b1v[16];
#pragma unroll
    for (int ks = 0; ks < 2; ++ks)
#pragma unroll
        for (int j = 0; j < 8; ++j) {
            w1v[ks * 8 + j] = W1f[ks * 32 + q * 8 + j];
            b1v[ks * 8 + j] = b1f[ks * 32 + q * 8 + j];
        }
    float b2v[4], w3v[4];
#pragma unroll
    for (int nt = 0; nt < 4; ++nt) {
        b2v[nt] = b2f[nt * 16 + col];
        w3v[nt] = W3f[nt * 16 + col];
    }
    const float b3f = b3[f];

    float x4[4];
#pragma unroll
    for (int mt = 0; mt < 4; ++mt)
        x4[mt] = inputs[(size_t)(b0 + w * 64 + mt * 16 + col) * F + f];

    __syncthreads();

    bf16x8 bhi[4][2], blo[4][2];
#pragma unroll
    for (int nt = 0; nt < 4; ++nt)
#pragma unroll
        for (int ks = 0; ks < 2; ++ks) {
            const int slot = (nt * 2 + ks) * 64 + lane;
            bhi[nt][ks] = *(bf16x8*)&bhi_s[slot * 8];
            blo[nt][ks] = *(bf16x8*)&blo_s[slot * 8];
        }

#pragma unroll 1
    for (int mt = 0; mt < 4; ++mt) {
        const int rbase = b0 + w * 64 + mt * 16;
        const float x = x4[mt];

        f32x4 acc[4];
#pragma unroll
        for (int nt = 0; nt < 4; ++nt) {
            acc[nt][0] = b2v[nt]; acc[nt][1] = b2v[nt];
            acc[nt][2] = b2v[nt]; acc[nt][3] = b2v[nt];
        }

#pragma unroll
        for (int ks = 0; ks < 2; ++ks) {
            union { unsigned int u[4]; bf16x8 v; } Ah, Al;
#pragma unroll
            for (int t = 0; t < 4; ++t) {
                const float r0 = fmaxf(fmaf(x, w1v[ks * 8 + 2 * t],     b1v[ks * 8 + 2 * t]),     0.0f);
                const float r1 = fmaxf(fmaf(x, w1v[ks * 8 + 2 * t + 1], b1v[ks * 8 + 2 * t + 1]), 0.0f);
                const unsigned int u0 = __float_as_uint(r0);
                const unsigned int u1 = __float_as_uint(r1);
                const float l0 = r0 - __uint_as_float(u0 & 0xFFFF0000u);
                const float l1 = r1 - __uint_as_float(u1 & 0xFFFF0000u);
                Ah.u[t] = __builtin_amdgcn_perm(u1, u0, 0x07060302);
                Al.u[t] = __builtin_amdgcn_perm(__float_as_uint(l1),
                                                __float_as_uint(l0), 0x07060302);
            }
#pragma unroll
            for (int nt = 0; nt < 4; ++nt) {
                acc[nt] = __builtin_amdgcn_mfma_f32_16x16x32_bf16(Ah.v, bhi[nt][ks], acc[nt], 0, 0, 0);
                acc[nt] = __builtin_amdgcn_mfma_f32_16x16x32_bf16(Ah.v, blo[nt][ks], acc[nt], 0, 0, 0);
                acc[nt] = __builtin_amdgcn_mfma_f32_16x16x32_bf16(Al.v, bhi[nt][ks], acc[nt], 0, 0, 0);
            }
        }

        float s[4];
#pragma unroll
        for (int reg = 0; reg < 4; ++reg) {
            float t = 0.0f;
#pragma unroll
            for (int nt = 0; nt < 4; ++nt)
                t = fmaf(fmaxf(acc[nt][reg], 0.0f), w3v[nt], t);
            s[reg] = t;
        }
#pragma unroll
        for (int m_ = 1; m_ <= 8; m_ <<= 1)
#pragma unroll
            for (int reg = 0; reg < 4; ++reg)
                s[reg] += __shfl_xor(s[reg], m_, 64);
        if (col == 0) {
#pragma unroll
            for (int reg = 0; reg < 4; ++reg) {
                const int row = rbase + 4 * q + reg;
                const float val = s[reg] + b3f;
                fnn_out[(size_t)row * F + f] = val;
                atomicAdd(&out[row], val);
            }
        }
    }
}

extern "C" void kernel_launch(void* const* d_in, const int* in_sizes, int n_in,
                              void* d_out, int out_size, void* d_ws, size_t ws_size,
                              hipStream_t stream) {
    const float* inputs = (const float*)d_in[0];
    const float* W1     = (const float*)d_in[1];
    const float* b1     = (const float*)d_in[2];
    const float* W2     = (const float*)d_in[3];
    const float* b2     = (const float*)d_in[4];
    const float* W3     = (const float*)d_in[5];
    const float* b3     = (const float*)d_in[6];

    float* out = (float*)d_out;   // (B,)
    float* fnn = out + B;         // (B, F)

    const size_t WS_NEEDED = (size_t)F * 4096 * 2 * sizeof(short)   // tables 2MB
                           + (size_t)F * B * sizeof(float);         // fnw 4MB

    if (ws_size >= WS_NEEDED) {
        short* bhi_g = (short*)d_ws;                        // 1 MB
        short* blo_g = bhi_g + (size_t)F * 4096;            // 1 MB
        float* fnw   = (float*)(blo_g + (size_t)F * 4096);  // 4 MB  (F, B)

        nam_prep<<<dim3(F), 256, 0, stream>>>(W2, bhi_g, blo_g);
        nam_main<<<dim3(B / 1024, F), 256, 0, stream>>>(inputs, W1, b1, bhi_g,
                                                        blo_g, b2, W3, b3, fnw);
        nam_finish<<<dim3(128), 256, 0, stream>>>(fnw, fnn, out);
    } else {
        hipMemsetAsync(out, 0, B * sizeof(float), stream);
        nam_mono<<<dim3(B / 256, F), 256, 0, stream>>>(inputs, W1, b1, W2, b2,
                                                       W3, b3, out, fnn);
    }
}

// Round 11
// 99.341 us; speedup vs baseline: 1.0280x; 1.0280x over previous
//
#include <hip/hip_runtime.h>

#define B 8192
#define F 128
#define H 64

typedef __attribute__((ext_vector_type(8))) short bf16x8;
typedef __attribute__((ext_vector_type(4))) float f32x4;

static __device__ __forceinline__ unsigned short f32_to_bf16_rne(float v) {
    unsigned int u = __float_as_uint(v);
    unsigned int r = (u + 0x7FFFu + ((u >> 16) & 1u)) >> 16;
    return (unsigned short)r;
}
static __device__ __forceinline__ float bf16_to_f32(unsigned short h) {
    return __uint_as_float(((unsigned int)h) << 16);
}

// global->LDS DMA; LDS dest is wave-uniform base + lane*size (linear);
// global src is PER-LANE (strided gathers allowed).
#define GLOAD_LDS16(gp, lp)                                                  \
    __builtin_amdgcn_global_load_lds(                                        \
        (const __attribute__((address_space(1))) unsigned int*)(gp),         \
        (__attribute__((address_space(3))) unsigned int*)(lp), 16, 0, 0)
#define GLOAD_LDS4(gp, lp)                                                   \
    __builtin_amdgcn_global_load_lds(                                        \
        (const __attribute__((address_space(1))) unsigned int*)(gp),         \
        (__attribute__((address_space(3))) unsigned int*)(lp), 4, 0, 0)

// Split-bf16 MFMA NAM.  Layer2 = 3x mfma_f32_16x16x32_bf16 (hh + hl + lh).
// R15: R14 (1024-block grid) regressed -2.9 -> startup theory falsified;
// grid reverted to R13's (16,F).  Plateau ledger: R11 occupancy null, R12
// unroll +1, R13 x-staging null, R14 grid -3.  Synthesis: unroll-2 was the
// only positive probe, and it was REGISTER-STARVED -- under (256,3) the
// allocator caps at ~85 VGPR (evidence: (256,4)->64, (256,3)->exactly 80)
// while the 16 B-fragments alone pin 64, so no second acc/A-frag set could
// stay live.  The R5/R8 catastrophe was the cap being too LOW.  Changes:
//   (1) nam_main __launch_bounds__(256,2): VGPR cap 256; unroll-2 can now
//       truly pipeline (expect ~110-135 VGPR; abort-signal = 64/FETCH
//       explosion).  Residency may drop; R11 proved occupancy irrelevant.
//   (2) nam_prep grid F -> 2F, one slot/thread (no loop): halves prep.
// Hard rules kept: never (256,4); LDS table via global_load_lds (linear
// dest); grid (16,F); x via pre-staged LDS; fire-and-forget LDS scatter
// epilogue + per-half reduce; ws guard + R4-mono fallback; no memset in
// fast path.

// ---- prep: 2F blocks, one slot/thread: W2 -> hi/lo bf16 B-fragment table ----
__global__ __launch_bounds__(256) void nam_prep(
    const float* __restrict__ W2, short* __restrict__ bhi_g,
    short* __restrict__ blo_g)
{
    const int tid = threadIdx.x;
    const int f = blockIdx.x >> 1;
    const int t = ((blockIdx.x & 1) << 8) | tid;   // slot index 0..511
    const float* W2f = W2 + (size_t)f * H * H;
    short* bhi = bhi_g + (size_t)f * 4096;
    short* blo = blo_g + (size_t)f * 4096;

    const int n = t & 63;          // output hidden index (MFMA n)
    const int g = t >> 6;          // h-group: h = g*8 + jj (MFMA k)
    const int nt = n >> 4, c = n & 15;
    const int ks = g >> 2, q = g & 3;
    const int slot = (nt * 2 + ks) * 64 + c + 16 * q;
    bf16x8 hv, lv;
#pragma unroll
    for (int jj = 0; jj < 8; ++jj) {
        const float wv = W2f[(g * 8 + jj) * H + n];
        const unsigned short hi = f32_to_bf16_rne(wv);
        const unsigned short lo = f32_to_bf16_rne(wv - bf16_to_f32(hi));
        hv[jj] = (short)hi;
        lv[jj] = (short)lo;
    }
    *(bf16x8*)&bhi[slot * 8] = hv;
    *(bf16x8*)&blo[slot * 8] = lv;
}

__global__ __launch_bounds__(256, 2) void nam_main(
    const float* __restrict__ inputs, const float* __restrict__ W1,
    const float* __restrict__ b1, const short* __restrict__ bhi_g,
    const short* __restrict__ blo_g, const float* __restrict__ b2,
    const float* __restrict__ W3, const float* __restrict__ b3,
    float* __restrict__ fnn_ws)
{
    const int tid = threadIdx.x;
    const int f = blockIdx.y;
    const int b0 = blockIdx.x * 512;   // 512 rows per block

    const int lane = tid & 63;
    const int w    = tid >> 6;
    const int q    = lane >> 4;   // quad
    const int col  = lane & 15;

    // per-wave partial-sum tile, 64 rows: row = (mt&3)*16+4q+reg, 16 cols,
    // pad to 18 f32 -> <=2-way bank aliasing (free).  Reduced after mt=3/7.
    __shared__ float s_tile[4][64][18];         // 18432 B
    __shared__ __align__(16) short bhs[4096];   // 8 KB
    __shared__ __align__(16) short bls[4096];   // 8 KB
    __shared__ float x_lds[4][128];             // 2 KB: per-wave x values

    // ---- DMA: table slice (16KB) + this wave's 128 x values, one drain ----
    {
        const short* bhi_f = bhi_g + (size_t)f * 4096;
        const short* blo_f = blo_g + (size_t)f * 4096;
#pragma unroll
        for (int c = w; c < 8; c += 4) {      // 2 chunks/table/wave
            GLOAD_LDS16(bhi_f + c * 512 + lane * 8, &bhs[c * 512]);
            GLOAD_LDS16(blo_f + c * 512 + lane * 8, &bls[c * 512]);
        }
        // x stage: rows [b0 + w*128, +128), strided 512B per-lane src,
        // linear lane*4 LDS dest.  Same addresses/bits as per-mt gathers.
        GLOAD_LDS4(inputs + (size_t)(b0 + w * 128 + lane) * F + f,
                   &x_lds[w][0]);
        GLOAD_LDS4(inputs + (size_t)(b0 + w * 128 + 64 + lane) * F + f,
                   &x_lds[w][64]);
    }

    // per-lane weight vectors (L2-hot broadcasts; overlap with DMA)
    const float* W1f = W1 + f * H;
    const float* b1f = b1 + f * H;
    float w1v[16], b1v[16];
#pragma unroll
    for (int ks = 0; ks < 2; ++ks)
#pragma unroll
        for (int j = 0; j < 8; ++j) {
            w1v[ks * 8 + j] = W1f[ks * 32 + q * 8 + j];
            b1v[ks * 8 + j] = b1f[ks * 32 + q * 8 + j];
        }
    const float* b2f = b2 + f * H;
    const float* W3f = W3 + f * H;
    float b2v[4], w3v[4];
#pragma unroll
    for (int nt = 0; nt < 4; ++nt) {
        b2v[nt] = b2f[nt * 16 + col];
        w3v[nt] = W3f[nt * 16 + col];
    }
    const float b3f = b3[f];

    __syncthreads();   // drains table DMA + x DMA together

    // ---- resident B fragments (LDS -> regs, once per block) ----
    bf16x8 bhi[4][2], blo[4][2];
#pragma unroll
    for (int nt = 0; nt < 4; ++nt)
#pragma unroll
        for (int ks = 0; ks < 2; ++ks) {
            const int slot = (nt * 2 + ks) * 64 + lane;
            bhi[nt][ks] = *(bf16x8*)&bhs[slot * 8];
            blo[nt][ks] = *(bf16x8*)&bls[slot * 8];
        }

    // ---- 8 m-tiles of 16 rows per wave; ZERO global loads in loop;
    // unroll 2 now has VGPR headroom to truly pipeline two mt bodies ----
#pragma unroll 2
    for (int mt = 0; mt < 8; ++mt) {
        // x via LDS: 16 addrs x 4-lane same-address multicast, conflict-free
        const float x = x_lds[w][(mt << 4) | col];

        f32x4 acc[4];
#pragma unroll
        for (int nt = 0; nt < 4; ++nt) {
            acc[nt][0] = b2v[nt]; acc[nt][1] = b2v[nt];
            acc[nt][2] = b2v[nt]; acc[nt][3] = b2v[nt];
        }

#pragma unroll
        for (int ks = 0; ks < 2; ++ks) {
            // A-frag: trunc-Dekker split, v_perm pair-packing.
            union { unsigned int u[4]; bf16x8 v; } Ah, Al;
#pragma unroll
            for (int t = 0; t < 4; ++t) {
                const float r0 = fmaxf(fmaf(x, w1v[ks * 8 + 2 * t],     b1v[ks * 8 + 2 * t]),     0.0f);
                const float r1 = fmaxf(fmaf(x, w1v[ks * 8 + 2 * t + 1], b1v[ks * 8 + 2 * t + 1]), 0.0f);
                const unsigned int u0 = __float_as_uint(r0);
                const unsigned int u1 = __float_as_uint(r1);
                const float l0 = r0 - __uint_as_float(u0 & 0xFFFF0000u);
                const float l1 = r1 - __uint_as_float(u1 & 0xFFFF0000u);
                Ah.u[t] = __builtin_amdgcn_perm(u1, u0, 0x07060302);
                Al.u[t] = __builtin_amdgcn_perm(__float_as_uint(l1),
                                                __float_as_uint(l0), 0x07060302);
            }
#pragma unroll
            for (int nt = 0; nt < 4; ++nt) {
                acc[nt] = __builtin_amdgcn_mfma_f32_16x16x32_bf16(Ah.v, bhi[nt][ks], acc[nt], 0, 0, 0);
                acc[nt] = __builtin_amdgcn_mfma_f32_16x16x32_bf16(Ah.v, blo[nt][ks], acc[nt], 0, 0, 0);
                acc[nt] = __builtin_amdgcn_mfma_f32_16x16x32_bf16(Al.v, bhi[nt][ks], acc[nt], 0, 0, 0);
            }
        }

        // ---- epilogue: fold W3 and scatter partials (fire-and-forget) ----
#pragma unroll
        for (int reg = 0; reg < 4; ++reg) {
            float t = 0.0f;
#pragma unroll
            for (int nt = 0; nt < 4; ++nt)
                t = fmaf(fmaxf(acc[nt][reg], 0.0f), w3v[nt], t);
            s_tile[w][(mt & 3) * 16 + 4 * q + reg][col] = t;
        }

        // ---- per-half reduce: 64 rows, 1 row/lane; coalesced 256B store ----
        if ((mt & 3) == 3) {
            float sum = 0.0f;
#pragma unroll
            for (int c = 0; c < 16; ++c)
                sum += s_tile[w][lane][c];
            float* dst = fnn_ws + (size_t)f * B + b0 + w * 128 + (mt >> 2) * 64;
            dst[lane] = sum + b3f;
        }
    }
}

// ---- finish: fnn_ws (F,B) -> fnn (B,F) transpose + out row-sums ----
// 128 blocks, each handles 64 rows x all 128 features: 'out' needs no
// atomics (full sum local to block) and no prior memset.
__global__ __launch_bounds__(256) void nam_finish(
    const float* __restrict__ fnn_ws, float* __restrict__ fnn,
    float* __restrict__ out)
{
    const int tid = threadIdx.x;
    const int r0 = blockIdx.x * 64;
    __shared__ float tile[128][65];    // 33280 B
    __shared__ float psum[4][64];

    float rsum = 0.0f;
#pragma unroll
    for (int j = 0; j < 32; ++j) {     // coalesced 256B/64-lane reads
        const int fl = j * 4 + (tid >> 6);
        const int rl = tid & 63;
        const float v = fnn_ws[(size_t)fl * B + r0 + rl];
        tile[fl][rl] = v;
        rsum += v;
    }
    psum[tid >> 6][tid & 63] = rsum;
    __syncthreads();
    if (tid < 64)                      // plain store; no atomic, no memset
        out[r0 + tid] = psum[0][tid] + psum[1][tid] + psum[2][tid] + psum[3][tid];

#pragma unroll
    for (int j = 0; j < 8; ++j) {      // fnn rows: 512B-contiguous float4 writes
        const int rl = j * 8 + (tid >> 5);
        const int c4 = tid & 31;
        f32x4 v;
        v[0] = tile[c4 * 4 + 0][rl];
        v[1] = tile[c4 * 4 + 1][rl];
        v[2] = tile[c4 * 4 + 2][rl];
        v[3] = tile[c4 * 4 + 3][rl];
        *(f32x4*)&fnn[(size_t)(r0 + rl) * F + c4 * 4] = v;
    }
}

// ---- fallback: proven R4 monolithic kernel (used only if ws too small) ----
__global__ __launch_bounds__(256, 3) void nam_mono(
    const float* __restrict__ inputs, const float* __restrict__ W1,
    const float* __restrict__ b1, const float* __restrict__ W2,
    const float* __restrict__ b2, const float* __restrict__ W3,
    const float* __restrict__ b3, float* __restrict__ out,
    float* __restrict__ fnn_out)
{
    const int tid = threadIdx.x;
    const int f = blockIdx.y;
    const int b0 = blockIdx.x * 256;

    const float* W1f = W1 + f * H;
    const float* b1f = b1 + f * H;
    const float* W2f = W2 + (size_t)f * H * H;
    const float* b2f = b2 + f * H;
    const float* W3f = W3 + f * H;

    __shared__ __align__(16) short bhi_s[512 * 8];
    __shared__ __align__(16) short blo_s[512 * 8];

#pragma unroll
    for (int t = tid; t < 512; t += 256) {
        const int n = t & 63;
        const int g = t >> 6;
        const int nt = n >> 4, c = n & 15;
        const int ks = g >> 2, q = g & 3;
        const int slot = (nt * 2 + ks) * 64 + c + 16 * q;
        bf16x8 hv, lv;
#pragma unroll
        for (int jj = 0; jj < 8; ++jj) {
            const float wv = W2f[(g * 8 + jj) * H + n];
            const unsigned short hi = f32_to_bf16_rne(wv);
            const unsigned short lo = f32_to_bf16_rne(wv - bf16_to_f32(hi));
            hv[jj] = (short)hi;
            lv[jj] = (short)lo;
        }
        *(bf16x8*)&bhi_s[slot * 8] = hv;
        *(bf16x8*)&blo_s[slot * 8] = lv;
    }

    const int lane = tid & 63;
    const int w    = tid >> 6;
    const int q    = lane >> 4;
    const int col  = lane & 15;

    float w1v[16], b1v[16];
#pragma unroll
    for (int ks = 0; ks < 2; ++ks)
#pragma unroll
        for (int j = 0; j < 8; ++j) {
            w1v[ks * 8 + j] = W1f[ks * 32 + q * 8 + j];
            b1v[ks * 8 + j] = b1f[ks * 32 + q * 8 + j];
        }
    float b2v[4], w3v[4];
#pragma unroll
    for (int nt = 0; nt < 4; ++nt) {
        b2v[nt] = b2f[nt * 16 + col];
        w3v[nt] = W3f[nt * 16 + col];
    }
    const float b3f = b3[f];

    float x4[4];
#pragma unroll
    for (int mt = 0; mt < 4; ++mt)
        x4[mt] = inputs[(size_t)(b0 + w * 64 + mt * 16 + col) * F + f];

    __syncthreads();

    bf16x8 bhi[4][2], blo[4][2];
#pragma unroll
    for (int nt = 0; nt < 4; ++nt)
#pragma unroll
        for (int ks = 0; ks < 2; ++ks) {
            const int slot = (nt * 2 + ks) * 64 + lane;
            bhi[nt][ks] = *(bf16x8*)&bhi_s[slot * 8];
            blo[nt][ks] = *(bf16x8*)&blo_s[slot * 8];
        }

#pragma unroll 1
    for (int mt = 0; mt < 4; ++mt) {
        const int rbase = b0 + w * 64 + mt * 16;
        const float x = x4[mt];

        f32x4 acc[4];
#pragma unroll
        for (int nt = 0; nt < 4; ++nt) {
            acc[nt][0] = b2v[nt]; acc[nt][1] = b2v[nt];
            acc[nt][2] = b2v[nt]; acc[nt][3] = b2v[nt];
        }

#pragma unroll
        for (int ks = 0; ks < 2; ++ks) {
            union { unsigned int u[4]; bf16x8 v; } Ah, Al;
#pragma unroll
            for (int t = 0; t < 4; ++t) {
                const float r0 = fmaxf(fmaf(x, w1v[ks * 8 + 2 * t],     b1v[ks * 8 + 2 * t]),     0.0f);
                const float r1 = fmaxf(fmaf(x, w1v[ks * 8 + 2 * t + 1], b1v[ks * 8 + 2 * t + 1]), 0.0f);
                const unsigned int u0 = __float_as_uint(r0);
                const unsigned int u1 = __float_as_uint(r1);
                const float l0 = r0 - __uint_as_float(u0 & 0xFFFF0000u);
                const float l1 = r1 - __uint_as_float(u1 & 0xFFFF0000u);
                Ah.u[t] = __builtin_amdgcn_perm(u1, u0, 0x07060302);
                Al.u[t] = __builtin_amdgcn_perm(__float_as_uint(l1),
                                                __float_as_uint(l0), 0x07060302);
            }
#pragma unroll
            for (int nt = 0; nt < 4; ++nt) {
                acc[nt] = __builtin_amdgcn_mfma_f32_16x16x32_bf16(Ah.v, bhi[nt][ks], acc[nt], 0, 0, 0);
                acc[nt] = __builtin_amdgcn_mfma_f32_16x16x32_bf16(Ah.v, blo[nt][ks], acc[nt], 0, 0, 0);
                acc[nt] = __builtin_amdgcn_mfma_f32_16x16x32_bf16(Al.v, bhi[nt][ks], acc[nt], 0, 0, 0);
            }
        }

        float s[4];
#pragma unroll
        for (int reg = 0; reg < 4; ++reg) {
            float t = 0.0f;
#pragma unroll
            for (int nt = 0; nt < 4; ++nt)
                t = fmaf(fmaxf(acc[nt][reg], 0.0f), w3v[nt], t);
            s[reg] = t;
        }
#pragma unroll
        for (int m_ = 1; m_ <= 8; m_ <<= 1)
#pragma unroll
            for (int reg = 0; reg < 4; ++reg)
                s[reg] += __shfl_xor(s[reg], m_, 64);
        if (col == 0) {
#pragma unroll
            for (int reg = 0; reg < 4; ++reg) {
                const int row = rbase + 4 * q + reg;
                const float val = s[reg] + b3f;
                fnn_out[(size_t)row * F + f] = val;
                atomicAdd(&out[row], val);
            }
        }
    }
}

extern "C" void kernel_launch(void* const* d_in, const int* in_sizes, int n_in,
                              void* d_out, int out_size, void* d_ws, size_t ws_size,
                              hipStream_t stream) {
    const float* inputs = (const float*)d_in[0];
    const float* W1     = (const float*)d_in[1];
    const float* b1     = (const float*)d_in[2];
    const float* W2     = (const float*)d_in[3];
    const float* b2     = (const float*)d_in[4];
    const float* W3     = (const float*)d_in[5];
    const float* b3     = (const float*)d_in[6];

    float* out = (float*)d_out;   // (B,)
    float* fnn = out + B;         // (B, F)

    const size_t WS_NEEDED = (size_t)F * 4096 * 2 * sizeof(short)   // tables 2MB
                           + (size_t)F * B * sizeof(float);         // fnw 4MB

    if (ws_size >= WS_NEEDED) {
        short* bhi_g = (short*)d_ws;                        // 1 MB
        short* blo_g = bhi_g + (size_t)F * 4096;            // 1 MB
        float* fnw   = (float*)(blo_g + (size_t)F * 4096);  // 4 MB  (F, B)

        nam_prep<<<dim3(2 * F), 256, 0, stream>>>(W2, bhi_g, blo_g);
        nam_main<<<dim3(B / 512, F), 256, 0, stream>>>(inputs, W1, b1, bhi_g,
                                                       blo_g, b2, W3, b3, fnw);
        nam_finish<<<dim3(128), 256, 0, stream>>>(fnw, fnn, out);
    } else {
        hipMemsetAsync(out, 0, B * sizeof(float), stream);
        nam_mono<<<dim3(B / 256, F), 256, 0, stream>>>(inputs, W1, b1, W2, b2,
                                                       W3, b3, out, fnn);
    }
}

// Round 12
// 93.130 us; speedup vs baseline: 1.0965x; 1.0667x over previous
//
#include <hip/hip_runtime.h>

#define B 8192
#define F 128
#define H 64

typedef __attribute__((ext_vector_type(8))) short bf16x8;
typedef __attribute__((ext_vector_type(4))) float f32x4;

static __device__ __forceinline__ unsigned short f32_to_bf16_rne(float v) {
    unsigned int u = __float_as_uint(v);
    unsigned int r = (u + 0x7FFFu + ((u >> 16) & 1u)) >> 16;
    return (unsigned short)r;
}
static __device__ __forceinline__ float bf16_to_f32(unsigned short h) {
    return __uint_as_float(((unsigned int)h) << 16);
}

// global->LDS DMA; LDS dest is wave-uniform base + lane*size (linear);
// global src is PER-LANE (strided gathers allowed).
#define GLOAD_LDS16(gp, lp)                                                  \
    __builtin_amdgcn_global_load_lds(                                        \
        (const __attribute__((address_space(1))) unsigned int*)(gp),         \
        (__attribute__((address_space(3))) unsigned int*)(lp), 16, 0, 0)
#define GLOAD_LDS4(gp, lp)                                                   \
    __builtin_amdgcn_global_load_lds(                                        \
        (const __attribute__((address_space(1))) unsigned int*)(gp),         \
        (__attribute__((address_space(3))) unsigned int*)(lp), 4, 0, 0)

// Split-bf16 MFMA NAM.
// R16: five structural probes (R11 occupancy, R12 unroll, R13 x-staging,
// R14 grid, R15 VGPR-headroom) all null -> main (~38-40us) is bound by its
// own instruction stream, not scheduling.  Cut the stream: Layer2 split
// reduced 3-term (hh+hl+lh) -> 2-term (Ah*Bhi + Ah*Blo), i.e. drop the
// A-lo path.  A-prep per ks: 8fma+8max+8and+8sub+8perm -> 8fma+8max+4perm
// (-50% VALU); MFMA 24 -> 16 per mt (-33%); A-prep->MFMA dep chain 5->3.
// Error analysis: dropped term |lo(h1)*W2| <= h1*2^-9*W2 -> Delta-out ~
// 3e-3, quadrature-invisible vs the 0.0625 floor (B-lo stays: it's free
// from the prep table).  Expected absmax <= ~0.08.
// Hard rules kept: __launch_bounds__(256,3) ((256,4) -> 64-VGPR spill
// catastrophe, twice measured); LDS table via global_load_lds (linear
// dest); grid (16,F); x via pre-staged LDS; fire-and-forget LDS scatter
// epilogue + per-half reduce; ws guard + R4-mono fallback (fallback keeps
// the proven 3-term numerics); no memset in fast path.

// ---- prep: 2F blocks, one slot/thread: W2 -> hi/lo bf16 B-fragment table ----
__global__ __launch_bounds__(256) void nam_prep(
    const float* __restrict__ W2, short* __restrict__ bhi_g,
    short* __restrict__ blo_g)
{
    const int tid = threadIdx.x;
    const int f = blockIdx.x >> 1;
    const int t = ((blockIdx.x & 1) << 8) | tid;   // slot index 0..511
    const float* W2f = W2 + (size_t)f * H * H;
    short* bhi = bhi_g + (size_t)f * 4096;
    short* blo = blo_g + (size_t)f * 4096;

    const int n = t & 63;          // output hidden index (MFMA n)
    const int g = t >> 6;          // h-group: h = g*8 + jj (MFMA k)
    const int nt = n >> 4, c = n & 15;
    const int ks = g >> 2, q = g & 3;
    const int slot = (nt * 2 + ks) * 64 + c + 16 * q;
    bf16x8 hv, lv;
#pragma unroll
    for (int jj = 0; jj < 8; ++jj) {
        const float wv = W2f[(g * 8 + jj) * H + n];
        const unsigned short hi = f32_to_bf16_rne(wv);
        const unsigned short lo = f32_to_bf16_rne(wv - bf16_to_f32(hi));
        hv[jj] = (short)hi;
        lv[jj] = (short)lo;
    }
    *(bf16x8*)&bhi[slot * 8] = hv;
    *(bf16x8*)&blo[slot * 8] = lv;
}

__global__ __launch_bounds__(256, 3) void nam_main(
    const float* __restrict__ inputs, const float* __restrict__ W1,
    const float* __restrict__ b1, const short* __restrict__ bhi_g,
    const short* __restrict__ blo_g, const float* __restrict__ b2,
    const float* __restrict__ W3, const float* __restrict__ b3,
    float* __restrict__ fnn_ws)
{
    const int tid = threadIdx.x;
    const int f = blockIdx.y;
    const int b0 = blockIdx.x * 512;   // 512 rows per block

    const int lane = tid & 63;
    const int w    = tid >> 6;
    const int q    = lane >> 4;   // quad
    const int col  = lane & 15;

    // per-wave partial-sum tile, 64 rows: row = (mt&3)*16+4q+reg, 16 cols,
    // pad to 18 f32 -> <=2-way bank aliasing (free).  Reduced after mt=3/7.
    __shared__ float s_tile[4][64][18];         // 18432 B
    __shared__ __align__(16) short bhs[4096];   // 8 KB
    __shared__ __align__(16) short bls[4096];   // 8 KB
    __shared__ float x_lds[4][128];             // 2 KB: per-wave x values

    // ---- DMA: table slice (16KB) + this wave's 128 x values, one drain ----
    {
        const short* bhi_f = bhi_g + (size_t)f * 4096;
        const short* blo_f = blo_g + (size_t)f * 4096;
#pragma unroll
        for (int c = w; c < 8; c += 4) {      // 2 chunks/table/wave
            GLOAD_LDS16(bhi_f + c * 512 + lane * 8, &bhs[c * 512]);
            GLOAD_LDS16(blo_f + c * 512 + lane * 8, &bls[c * 512]);
        }
        // x stage: rows [b0 + w*128, +128), strided 512B per-lane src,
        // linear lane*4 LDS dest.  Same addresses/bits as per-mt gathers.
        GLOAD_LDS4(inputs + (size_t)(b0 + w * 128 + lane) * F + f,
                   &x_lds[w][0]);
        GLOAD_LDS4(inputs + (size_t)(b0 + w * 128 + 64 + lane) * F + f,
                   &x_lds[w][64]);
    }

    // per-lane weight vectors (L2-hot broadcasts; overlap with DMA)
    const float* W1f = W1 + f * H;
    const float* b1f = b1 + f * H;
    float w1v[16], b1v[16];
#pragma unroll
    for (int ks = 0; ks < 2; ++ks)
#pragma unroll
        for (int j = 0; j < 8; ++j) {
            w1v[ks * 8 + j] = W1f[ks * 32 + q * 8 + j];
            b1v[ks * 8 + j] = b1f[ks * 32 + q * 8 + j];
        }
    const float* b2f = b2 + f * H;
    const float* W3f = W3 + f * H;
    float b2v[4], w3v[4];
#pragma unroll
    for (int nt = 0; nt < 4; ++nt) {
        b2v[nt] = b2f[nt * 16 + col];
        w3v[nt] = W3f[nt * 16 + col];
    }
    const float b3f = b3[f];

    __syncthreads();   // drains table DMA + x DMA together

    // ---- resident B fragments (LDS -> regs, once per block) ----
    bf16x8 bhi[4][2], blo[4][2];
#pragma unroll
    for (int nt = 0; nt < 4; ++nt)
#pragma unroll
        for (int ks = 0; ks < 2; ++ks) {
            const int slot = (nt * 2 + ks) * 64 + lane;
            bhi[nt][ks] = *(bf16x8*)&bhs[slot * 8];
            blo[nt][ks] = *(bf16x8*)&bls[slot * 8];
        }

    // ---- 8 m-tiles of 16 rows per wave; ZERO global loads in loop ----
#pragma unroll 2
    for (int mt = 0; mt < 8; ++mt) {
        // x via LDS: 16 addrs x 4-lane same-address multicast, conflict-free
        const float x = x_lds[w][(mt << 4) | col];

        f32x4 acc[4];
#pragma unroll
        for (int nt = 0; nt < 4; ++nt) {
            acc[nt][0] = b2v[nt]; acc[nt][1] = b2v[nt];
            acc[nt][2] = b2v[nt]; acc[nt][3] = b2v[nt];
        }

#pragma unroll
        for (int ks = 0; ks < 2; ++ks) {
            // A-frag: h1 truncated to bf16 via v_perm top-half packing.
            // 2-term split: A-lo path dropped (R16) -- B's lo (free from
            // the prep table) still compensates W2's rounding.
            union { unsigned int u[4]; bf16x8 v; } Ah;
#pragma unroll
            for (int t = 0; t < 4; ++t) {
                const float r0 = fmaxf(fmaf(x, w1v[ks * 8 + 2 * t],     b1v[ks * 8 + 2 * t]),     0.0f);
                const float r1 = fmaxf(fmaf(x, w1v[ks * 8 + 2 * t + 1], b1v[ks * 8 + 2 * t + 1]), 0.0f);
                Ah.u[t] = __builtin_amdgcn_perm(__float_as_uint(r1),
                                                __float_as_uint(r0), 0x07060302);
            }
#pragma unroll
            for (int nt = 0; nt < 4; ++nt) {
                acc[nt] = __builtin_amdgcn_mfma_f32_16x16x32_bf16(Ah.v, bhi[nt][ks], acc[nt], 0, 0, 0);
                acc[nt] = __builtin_amdgcn_mfma_f32_16x16x32_bf16(Ah.v, blo[nt][ks], acc[nt], 0, 0, 0);
            }
        }

        // ---- epilogue: fold W3 and scatter partials (fire-and-forget) ----
#pragma unroll
        for (int reg = 0; reg < 4; ++reg) {
            float t = 0.0f;
#pragma unroll
            for (int nt = 0; nt < 4; ++nt)
                t = fmaf(fmaxf(acc[nt][reg], 0.0f), w3v[nt], t);
            s_tile[w][(mt & 3) * 16 + 4 * q + reg][col] = t;
        }

        // ---- per-half reduce: 64 rows, 1 row/lane; coalesced 256B store ----
        if ((mt & 3) == 3) {
            float sum = 0.0f;
#pragma unroll
            for (int c = 0; c < 16; ++c)
                sum += s_tile[w][lane][c];
            float* dst = fnn_ws + (size_t)f * B + b0 + w * 128 + (mt >> 2) * 64;
            dst[lane] = sum + b3f;
        }
    }
}

// ---- finish: fnn_ws (F,B) -> fnn (B,F) transpose + out row-sums ----
// 128 blocks, each handles 64 rows x all 128 features: 'out' needs no
// atomics (full sum local to block) and no prior memset.
__global__ __launch_bounds__(256) void nam_finish(
    const float* __restrict__ fnn_ws, float* __restrict__ fnn,
    float* __restrict__ out)
{
    const int tid = threadIdx.x;
    const int r0 = blockIdx.x * 64;
    __shared__ float tile[128][65];    // 33280 B
    __shared__ float psum[4][64];

    float rsum = 0.0f;
#pragma unroll
    for (int j = 0; j < 32; ++j) {     // coalesced 256B/64-lane reads
        const int fl = j * 4 + (tid >> 6);
        const int rl = tid & 63;
        const float v = fnn_ws[(size_t)fl * B + r0 + rl];
        tile[fl][rl] = v;
        rsum += v;
    }
    psum[tid >> 6][tid & 63] = rsum;
    __syncthreads();
    if (tid < 64)                      // plain store; no atomic, no memset
        out[r0 + tid] = psum[0][tid] + psum[1][tid] + psum[2][tid] + psum[3][tid];

#pragma unroll
    for (int j = 0; j < 8; ++j) {      // fnn rows: 512B-contiguous float4 writes
        const int rl = j * 8 + (tid >> 5);
        const int c4 = tid & 31;
        f32x4 v;
        v[0] = tile[c4 * 4 + 0][rl];
        v[1] = tile[c4 * 4 + 1][rl];
        v[2] = tile[c4 * 4 + 2][rl];
        v[3] = tile[c4 * 4 + 3][rl];
        *(f32x4*)&fnn[(size_t)(r0 + rl) * F + c4 * 4] = v;
    }
}

// ---- fallback: proven R4 monolithic kernel (used only if ws too small) ----
__global__ __launch_bounds__(256, 3) void nam_mono(
    const float* __restrict__ inputs, const float* __restrict__ W1,
    const float* __restrict__ b1, const float* __restrict__ W2,
    const float* __restrict__ b2, const float* __restrict__ W3,
    const float* __restrict__ b3, float* __restrict__ out,
    float* __restrict__ fnn_out)
{
    const int tid = threadIdx.x;
    const int f = blockIdx.y;
    const int b0 = blockIdx.x * 256;

    const float* W1f = W1 + f * H;
    const float* b1f = b1 + f * H;
    const float* W2f = W2 + (size_t)f * H * H;
    const float* b2f = b2 + f * H;
    const float* W3f = W3 + f * H;

    __shared__ __align__(16) short bhi_s[512 * 8];
    __shared__ __align__(16) short blo_s[512 * 8];

#pragma unroll
    for (int t = tid; t < 512; t += 256) {
        const int n = t & 63;
        const int g = t >> 6;
        const int nt = n >> 4, c = n & 15;
        const int ks = g >> 2, q = g & 3;
        const int slot = (nt * 2 + ks) * 64 + c + 16 * q;
        bf16x8 hv, lv;
#pragma unroll
        for (int jj = 0; jj < 8; ++jj) {
            const float wv = W2f[(g * 8 + jj) * H + n];
            const unsigned short hi = f32_to_bf16_rne(wv);
            const unsigned short lo = f32_to_bf16_rne(wv - bf16_to_f32(hi));
            hv[jj] = (short)hi;
            lv[jj] = (short)lo;
        }
        *(bf16x8*)&bhi_s[slot * 8] = hv;
        *(bf16x8*)&blo_s[slot * 8] = lv;
    }

    const int lane = tid & 63;
    const int w    = tid >> 6;
    const int q    = lane >> 4;
    const int col  = lane & 15;

    float w1v[16], b1v[16];
#pragma unroll
    for (int ks = 0; ks < 2; ++ks)
#pragma unroll
        for (int j = 0; j < 8; ++j) {
            w1v[ks * 8 + j] = W1f[ks * 32 + q * 8 + j];
            b1v[ks * 8 + j] = b1f[ks * 32 + q * 8 + j];
        }
    float b2v[4], w3v[4];
#pragma unroll
    for (int nt = 0; nt < 4; ++nt) {
        b2v[nt] = b2f[nt * 16 + col];
        w3v[nt] = W3f[nt * 16 + col];
    }
    const float b3f = b3[f];

    float x4[4];
#pragma unroll
    for (int mt = 0; mt < 4; ++mt)
        x4[mt] = inputs[(size_t)(b0 + w * 64 + mt * 16 + col) * F + f];

    __syncthreads();

    bf16x8 bhi[4][2], blo[4][2];
#pragma unroll
    for (int nt = 0; nt < 4; ++nt)
#pragma unroll
        for (int ks = 0; ks < 2; ++ks) {
            const int slot = (nt * 2 + ks) * 64 + lane;
            bhi[nt][ks] = *(bf16x8*)&bhi_s[slot * 8];
            blo[nt][ks] = *(bf16x8*)&blo_s[slot * 8];
        }

#pragma unroll 1
    for (int mt = 0; mt < 4; ++mt) {
        const int rbase = b0 + w * 64 + mt * 16;
        const float x = x4[mt];

        f32x4 acc[4];
#pragma unroll
        for (int nt = 0; nt < 4; ++nt) {
            acc[nt][0] = b2v[nt]; acc[nt][1] = b2v[nt];
            acc[nt][2] = b2v[nt]; acc[nt][3] = b2v[nt];
        }

#pragma unroll
        for (int ks = 0; ks < 2; ++ks) {
            union { unsigned int u[4]; bf16x8 v; } Ah, Al;
#pragma unroll
            for (int t = 0; t < 4; ++t) {
                const float r0 = fmaxf(fmaf(x, w1v[ks * 8 + 2 * t],     b1v[ks * 8 + 2 * t]),     0.0f);
                const float r1 = fmaxf(fmaf(x, w1v[ks * 8 + 2 * t + 1], b1v[ks * 8 + 2 * t + 1]), 0.0f);
                const unsigned int u0 = __float_as_uint(r0);
                const unsigned int u1 = __float_as_uint(r1);
                const float l0 = r0 - __uint_as_float(u0 & 0xFFFF0000u);
                const float l1 = r1 - __uint_as_float(u1 & 0xFFFF0000u);
                Ah.u[t] = __builtin_amdgcn_perm(u1, u0, 0x07060302);
                Al.u[t] = __builtin_amdgcn_perm(__float_as_uint(l1),
                                                __float_as_uint(l0), 0x07060302);
            }
#pragma unroll
            for (int nt = 0; nt < 4; ++nt) {
                acc[nt] = __builtin_amdgcn_mfma_f32_16x16x32_bf16(Ah.v, bhi[nt][ks], acc[nt], 0, 0, 0);
                acc[nt] = __builtin_amdgcn_mfma_f32_16x16x32_bf16(Ah.v, blo[nt][ks], acc[nt], 0, 0, 0);
                acc[nt] = __builtin_amdgcn_mfma_f32_16x16x32_bf16(Al.v, bhi[nt][ks], acc[nt], 0, 0, 0);
            }
        }

        float s[4];
#pragma unroll
        for (int reg = 0; reg < 4; ++reg) {
            float t = 0.0f;
#pragma unroll
            for (int nt = 0; nt < 4; ++nt)
                t = fmaf(fmaxf(acc[nt][reg], 0.0f), w3v[nt], t);
            s[reg] = t;
        }
#pragma unroll
        for (int m_ = 1; m_ <= 8; m_ <<= 1)
#pragma unroll
            for (int reg = 0; reg < 4; ++reg)
                s[reg] += __shfl_xor(s[reg], m_, 64);
        if (col == 0) {
#pragma unroll
            for (int reg = 0; reg < 4; ++reg) {
                const int row = rbase + 4 * q + reg;
                const float val = s[reg] + b3f;
                fnn_out[(size_t)row * F + f] = val;
                atomicAdd(&out[row], val);
            }
        }
    }
}

extern "C" void kernel_launch(void* const* d_in, const int* in_sizes, int n_in,
                              void* d_out, int out_size, void* d_ws, size_t ws_size,
                              hipStream_t stream) {
    const float* inputs = (const float*)d_in[0];
    const float* W1     = (const float*)d_in[1];
    const float* b1     = (const float*)d_in[2];
    const float* W2     = (const float*)d_in[3];
    const float* b2     = (const float*)d_in[4];
    const float* W3     = (const float*)d_in[5];
    const float* b3     = (const float*)d_in[6];

    float* out = (float*)d_out;   // (B,)
    float* fnn = out + B;         // (B, F)

    const size_t WS_NEEDED = (size_t)F * 4096 * 2 * sizeof(short)   // tables 2MB
                           + (size_t)F * B * sizeof(float);         // fnw 4MB

    if (ws_size >= WS_NEEDED) {
        short* bhi_g = (short*)d_ws;                        // 1 MB
        short* blo_g = bhi_g + (size_t)F * 4096;            // 1 MB
        float* fnw   = (float*)(blo_g + (size_t)F * 4096);  // 4 MB  (F, B)

        nam_prep<<<dim3(2 * F), 256, 0, stream>>>(W2, bhi_g, blo_g);
        nam_main<<<dim3(B / 512, F), 256, 0, stream>>>(inputs, W1, b1, bhi_g,
                                                       blo_g, b2, W3, b3, fnw);
        nam_finish<<<dim3(128), 256, 0, stream>>>(fnw, fnn, out);
    } else {
        hipMemsetAsync(out, 0, B * sizeof(float), stream);
        nam_mono<<<dim3(B / 256, F), 256, 0, stream>>>(inputs, W1, b1, W2, b2,
                                                       W3, b3, out, fnn);
    }
}